// Round 12
// baseline (191.244 us; speedup 1.0000x reference)
//
#include <hip/hip_runtime.h>

typedef float f32x4 __attribute__((ext_vector_type(4)));
typedef _Float16 h16;
typedef h16 half8 __attribute__((ext_vector_type(8)));

__device__ __forceinline__ float fast_tanh(float x) {
    float e = __expf(2.0f * x);
    return fmaf(-2.0f, __builtin_amdgcn_rcpf(e + 1.0f), 1.0f);
}
__device__ __forceinline__ half8 cvt8(float4 u0, float4 u1) {
    return (half8){(h16)u0.x,(h16)u0.y,(h16)u0.z,(h16)u0.w,
                   (h16)u1.x,(h16)u1.y,(h16)u1.z,(h16)u1.w};
}

#define S2IMGH 1576   // s2 halves per image: [196 pos + 1 pad][8 ch]

// ============================ K1: C1 via Toeplitz MFMA ============================
// 8 img/block. A-fragments load straight from global x (f32->f16 in regs).
// Epilogue writes pooled s2 to LDS; coalesced half8 flush to s2g.
// CRITICAL: s2l is zero-initialized — ch 6/7 + pad chunk are never written by
// the main loop, and uninitialized LDS flushed to s2g fed NaN into k_c3's
// MFMA (NaN*0 = NaN). That was round 11's failure.
#define C1_IMG 8

__global__ __launch_bounds__(256) void k_c1(
    const float* __restrict__ x, const float* __restrict__ c1_w,
    const float* __restrict__ c1_b, h16* __restrict__ s2g, int B)
{
    __shared__ __align__(16) h16 s2l[C1_IMG * S2IMGH];   // 25,216 B
    __shared__ float c1w_s[152];
    __shared__ float c1b_s[8];

    const int tid  = threadIdx.x;
    const int img0 = blockIdx.x * C1_IMG;
    const int nimg = min(C1_IMG, B - img0);
    if (nimg <= 0) return;

    if (tid < 150) c1w_s[tid] = c1_w[tid];
    if (tid < 6)   c1b_s[tid] = c1_b[tid];
    // zero-init s2l (NaN hygiene for ch6/7 + pad)
    {
        const half8 z = {(h16)0,(h16)0,(h16)0,(h16)0,(h16)0,(h16)0,(h16)0,(h16)0};
        half8* zp = (half8*)s2l;
        for (int i = tid; i < C1_IMG * 197; i += 256) zp[i] = z;
    }
    __syncthreads();

    const int lane = tid & 63, wv = tid >> 6;
    const int nloc = lane & 15, q4 = lane >> 4;

    // ---- Toeplitz B fragments: wave wv owns n-tiles 3wv..3wv+2 (round-10 proven) ----
    half8 bf[3][5];
    float bias[3];
    #pragma unroll
    for (int t = 0; t < 3; ++t) {
        const int tile = 3 * wv + t;
        const int map  = tile >> 1;
        const int j    = ((tile & 1) << 4) + nloc;
        bias[t] = c1b_s[map];
        #pragma unroll
        for (int ks = 0; ks < 5; ++ks) {
            half8 f;
            #pragma unroll
            for (int jj = 0; jj < 8; ++jj) {
                const int d = q4 * 8 + jj - j;
                f[jj] = (d >= 0 && d < 5) ? (h16)c1w_s[map * 25 + ks * 5 + d] : (h16)0;
            }
            bf[t][ks] = f;
        }
    }

    // ---- A rows from global: m-row = (img = nloc>>1, half = nloc&1) ----
    const int imgL = nloc >> 1, hf = nloc & 1;
    const int imgC = min(imgL, nimg - 1);               // tail clamp (no OOB)
    const float* xg = x + (size_t)(img0 + imgC) * 1024 + hf * (14 * 32) + q4 * 8;
    half8 rf[5];
    #pragma unroll
    for (int r = 0; r < 5; ++r)
        rf[r] = cvt8(*(const float4*)(xg + r * 32), *(const float4*)(xg + r * 32 + 4));

    float t0[3][4];
    for (int cr = 0; cr < 14; ++cr) {
        f32x4 acc[3];
        #pragma unroll
        for (int t = 0; t < 3; ++t) acc[t] = (f32x4){0.f, 0.f, 0.f, 0.f};
        #pragma unroll
        for (int ks = 0; ks < 5; ++ks) {
            #pragma unroll
            for (int t = 0; t < 3; ++t)
                acc[t] = __builtin_amdgcn_mfma_f32_16x16x32_f16(rf[ks], bf[t][ks], acc[t], 0, 0, 0);
        }
        if ((cr & 1) == 0) {
            #pragma unroll
            for (int t = 0; t < 3; ++t)
                #pragma unroll
                for (int r = 0; r < 4; ++r)
                    t0[t][r] = fast_tanh(acc[t][r] + bias[t]);
        } else {
            #pragma unroll
            for (int t = 0; t < 3; ++t) {
                const int tile = 3 * wv + t;
                const int jp   = (((tile & 1) << 4) + nloc) >> 1;
                const int map  = tile >> 1;
                #pragma unroll
                for (int r = 0; r < 4; ++r) {
                    float s = t0[t][r] + fast_tanh(acc[t][r] + bias[t]);
                    float o = 0.25f * (s + __shfl_xor(s, 1));
                    const int m = q4 * 4 + r;                 // C/D row = m
                    const int img = m >> 1, mh = m & 1;
                    const int ip  = (cr >> 1) + 7 * mh;
                    if (!(lane & 1) && jp < 14)
                        s2l[img * S2IMGH + (ip * 14 + jp) * 8 + map] = (h16)o;
                }
            }
        }
        if (cr < 13) {
            rf[0] = rf[1]; rf[1] = rf[2]; rf[2] = rf[3]; rf[3] = rf[4];
            rf[4] = cvt8(*(const float4*)(xg + (cr + 5) * 32),
                         *(const float4*)(xg + (cr + 5) * 32 + 4));
        }
    }
    __syncthreads();

    // ---- coalesced flush: 8 imgs x 197 half8 chunks ----
    for (int i = tid; i < C1_IMG * 197; i += 256) {
        const int img = i / 197, c = i % 197;
        if (img < nimg)
            *(half8*)(s2g + (size_t)(img0 + img) * S2IMGH + c * 8) =
                *(const half8*)(s2l + img * S2IMGH + c * 8);
    }
}

// ============================ K2: C3 MFMA + tanh + pool ============================
// B fragments built per-lane in registers; LDS 50.4 KB -> 3 blk/CU.
__device__ __constant__ int C3_INV[16][6] = {
    {0,1,2,-1,-1,-1},{-1,0,1,2,-1,-1},{-1,-1,0,1,2,-1},{-1,-1,-1,0,1,2},
    {0,-1,-1,-1,1,2},{0,1,-1,-1,-1,2},
    {0,1,2,3,-1,-1},{-1,0,1,2,3,-1},{-1,-1,0,1,2,3},{0,-1,-1,1,2,3},
    {0,1,-1,-1,2,3},{0,1,2,-1,-1,3},{0,1,-1,2,3,-1},{-1,0,1,-1,2,3},
    {0,-1,1,2,-1,3},
    {0,1,2,3,4,5}
};

__global__ __launch_bounds__(256) void k_c3(
    const h16* __restrict__ s2g,
    const float* __restrict__ c3_w3, const float* __restrict__ c3_b3,
    const float* __restrict__ c3_w4, const float* __restrict__ c3_b4,
    const float* __restrict__ c3_w6, const float* __restrict__ c3_b6,
    h16* __restrict__ s4g, int B)
{
    __shared__ __align__(16) h16 s2i[16 * S2IMGH];     // 50,432 B

    const int tid  = threadIdx.x;
    const int img0 = blockIdx.x * 16;
    const int nimg = min(16, B - img0);
    if (nimg <= 0) return;

    // coalesced staging: 16 imgs x 197 half8 chunks (zero-fill missing imgs)
    {
        const half8 z = {(h16)0,(h16)0,(h16)0,(h16)0,(h16)0,(h16)0,(h16)0,(h16)0};
        const int img = tid >> 4;
        for (int c = (tid & 15); c < 197; c += 16)
            *(half8*)(s2i + img * S2IMGH + c * 8) =
                (img < nimg) ? *(const half8*)(s2g + (size_t)(img0 + img) * S2IMGH + c * 8)
                             : z;
    }

    const int lane = tid & 63, wv = tid >> 6;
    const int nloc = lane & 15, q4 = lane >> 4;

    // ---- build B fragments in registers (mapping identical to old LDS panel) ----
    half8 bf[7];
    #pragma unroll
    for (int t = 0; t < 7; ++t) {
        half8 f;
        int dr, dc; bool valid = true;
        if (t <= 4)      { dr = q4; dc = t; }
        else if (t == 5) { dr = 4; dc = q4; }
        else             { dr = 4; dc = 4; valid = (q4 == 0); }
        #pragma unroll
        for (int j = 0; j < 8; ++j) {
            float val = 0.0f;
            if (valid && j < 6) {
                const int cc = C3_INV[nloc][j];
                if (cc >= 0) {
                    const int off = dr * 5 + dc;
                    if (nloc < 6)       val = c3_w3[(nloc * 3 + cc) * 25 + off];
                    else if (nloc < 15) val = c3_w4[((nloc - 6) * 4 + cc) * 25 + off];
                    else                val = c3_w6[cc * 25 + off];
                }
            }
            f[j] = (h16)val;
        }
        bf[t] = f;
    }
    const float bias = (nloc < 6) ? c3_b3[nloc]
                     : (nloc < 15) ? c3_b4[nloc - 6] : c3_b6[0];
    __syncthreads();

    // MFMA phase (round-9/10 proven)
    {
        const int abase = nloc * S2IMGH;
        for (int q = wv; q < 25; q += 4) {
            const int pr = q / 5, pc = q % 5;
            f32x4 acc[2][2];
            #pragma unroll
            for (int a = 0; a < 2; ++a)
                #pragma unroll
                for (int b2 = 0; b2 < 2; ++b2)
                    acc[a][b2] = (f32x4){0.f, 0.f, 0.f, 0.f};
            #pragma unroll
            for (int a = 0; a < 2; ++a) {
                #pragma unroll
                for (int b2 = 0; b2 < 2; ++b2) {
                    const int r = 2 * pr + a, col = 2 * pc + b2;
                    #pragma unroll
                    for (int t = 0; t < 5; ++t) {
                        half8 A = *(const half8*)(s2i + abase + ((r + q4) * 14 + col + t) * 8);
                        acc[a][b2] = __builtin_amdgcn_mfma_f32_16x16x32_f16(A, bf[t], acc[a][b2], 0, 0, 0);
                    }
                    half8 A5 = *(const half8*)(s2i + abase + ((r + 4) * 14 + col + q4) * 8);
                    acc[a][b2] = __builtin_amdgcn_mfma_f32_16x16x32_f16(A5, bf[5], acc[a][b2], 0, 0, 0);
                    half8 A6 = *(const half8*)(s2i + abase + ((r + 4) * 14 + col + 4) * 8);
                    acc[a][b2] = __builtin_amdgcn_mfma_f32_16x16x32_f16(A6, bf[6], acc[a][b2], 0, 0, 0);
                }
            }
            const int pos = pr * 5 + pc;
            #pragma unroll
            for (int rr = 0; rr < 4; ++rr) {
                const int img = q4 * 4 + rr;
                if (img < nimg) {
                    float s = fast_tanh(acc[0][0][rr] + bias) + fast_tanh(acc[0][1][rr] + bias)
                            + fast_tanh(acc[1][0][rr] + bias) + fast_tanh(acc[1][1][rr] + bias);
                    s4g[(size_t)(img0 + img) * 400 + nloc * 25 + pos] = (h16)(0.25f * s);
                }
            }
        }
    }
}

// ============================ K3: tail as 3 chained MFMA GEMMs ============================
// (unchanged from round 9/10)
#define KT_IMG   16
#define S4L_STR  424
#define C5O_STR  136
#define F6L_STR  104
#define KT_S4L   0
#define KT_C5OL  (KT_IMG * S4L_STR * 2)
#define KT_F6L   (KT_C5OL + KT_IMG * C5O_STR * 2)
#define KT_BIAS  (KT_F6L + KT_IMG * F6L_STR * 2)
#define KT_SMEM  (KT_BIAS + 240 * 4)

__global__ __launch_bounds__(256) void k_tail(
    const h16* __restrict__ s4g,
    const float* __restrict__ c5_w, const float* __restrict__ c5_b,
    const float* __restrict__ l1_w, const float* __restrict__ l1_b,
    const float* __restrict__ l2_w, const float* __restrict__ l2_b,
    float* __restrict__ out, int B)
{
    __shared__ __align__(16) char smem[KT_SMEM];
    h16*   s4l   = (h16*)(smem + KT_S4L);
    h16*   c5ol  = (h16*)(smem + KT_C5OL);
    h16*   f6l   = (h16*)(smem + KT_F6L);
    float* c5b_s = (float*)(smem + KT_BIAS);
    float* l1b_s = c5b_s + 128;
    float* l2b_s = l1b_s + 96;

    const int tid  = threadIdx.x;
    const int img0 = blockIdx.x * KT_IMG;
    const int nimg = min(KT_IMG, B - img0);
    if (nimg <= 0) return;

    if (tid < 128)      c5b_s[tid] = (tid < 120) ? c5_b[tid] : 0.f;
    else if (tid < 224) { int i = tid - 128; l1b_s[i] = (i < 84) ? l1_b[i] : 0.f; }
    else if (tid < 240) { int i = tid - 224; l2b_s[i] = (i < 10) ? l2_b[i] : 0.f; }

    {
        const half8 z = {(h16)0,(h16)0,(h16)0,(h16)0,(h16)0,(h16)0,(h16)0,(h16)0};
        for (int i = tid; i < KT_IMG * 53; i += 256) {
            int img = i / 53, cc = i % 53;
            half8 v = z;
            if (img < nimg && cc < 50)
                v = *(const half8*)(s4g + (size_t)(img0 + img) * 400 + cc * 8);
            *(half8*)(s4l + img * S4L_STR + cc * 8) = v;
        }
    }
    __syncthreads();

    const int lane = tid & 63, wv = tid >> 6;
    const int nloc = lane & 15, q4 = lane >> 4;
    const half8 z8 = {(h16)0,(h16)0,(h16)0,(h16)0,(h16)0,(h16)0,(h16)0,(h16)0};

    // ===== C5 =====
    {
        const int nb = wv * 2;
        f32x4 acc[2];
        acc[0] = (f32x4){0.f,0.f,0.f,0.f};
        acc[1] = (f32x4){0.f,0.f,0.f,0.f};
        for (int ks = 0; ks < 13; ++ks) {
            const int ka = ks * 32 + q4 * 8;
            half8 A = *(const half8*)(s4l + nloc * S4L_STR + ka);
            #pragma unroll
            for (int t = 0; t < 2; ++t) {
                const int n = (nb + t) * 16 + nloc;
                half8 Bf = z8;
                if (n < 120 && ka < 400) {
                    float4 u0 = *(const float4*)(c5_w + n * 400 + ka);
                    float4 u1 = *(const float4*)(c5_w + n * 400 + ka + 4);
                    Bf = cvt8(u0, u1);
                }
                acc[t] = __builtin_amdgcn_mfma_f32_16x16x32_f16(A, Bf, acc[t], 0, 0, 0);
            }
        }
        #pragma unroll
        for (int t = 0; t < 2; ++t) {
            const int o = (nb + t) * 16 + nloc;
            const float bo = c5b_s[o];
            #pragma unroll
            for (int r = 0; r < 4; ++r) {
                const int img = q4 * 4 + r;
                c5ol[img * C5O_STR + o] = (h16)fast_tanh(acc[t][r] + bo);
            }
        }
    }
    __syncthreads();

    // ===== F6 =====
    if (wv < 3) {
        const int nb = wv * 2;
        f32x4 acc[2];
        acc[0] = (f32x4){0.f,0.f,0.f,0.f};
        acc[1] = (f32x4){0.f,0.f,0.f,0.f};
        for (int ks = 0; ks < 4; ++ks) {
            const int ka = ks * 32 + q4 * 8;
            half8 A = *(const half8*)(c5ol + nloc * C5O_STR + ka);
            #pragma unroll
            for (int t = 0; t < 2; ++t) {
                const int n = (nb + t) * 16 + nloc;
                half8 Bf = z8;
                if (n < 84 && ka < 120) {
                    float4 u0 = *(const float4*)(l1_w + n * 120 + ka);
                    float4 u1 = *(const float4*)(l1_w + n * 120 + ka + 4);
                    Bf = cvt8(u0, u1);
                }
                acc[t] = __builtin_amdgcn_mfma_f32_16x16x32_f16(A, Bf, acc[t], 0, 0, 0);
            }
        }
        #pragma unroll
        for (int t = 0; t < 2; ++t) {
            const int o = (nb + t) * 16 + nloc;
            const float bo = l1b_s[o];
            #pragma unroll
            for (int r = 0; r < 4; ++r) {
                const int img = q4 * 4 + r;
                f6l[img * F6L_STR + o] = (h16)fast_tanh(acc[t][r] + bo);
            }
        }
    }
    __syncthreads();

    // ===== OUT =====
    if (wv == 0) {
        f32x4 acc = (f32x4){0.f,0.f,0.f,0.f};
        #pragma unroll
        for (int ks = 0; ks < 3; ++ks) {
            const int ka = ks * 32 + q4 * 8;
            half8 A = *(const half8*)(f6l + nloc * F6L_STR + ka);
            half8 Bf = z8;
            #pragma unroll
            for (int i = 0; i < 8; ++i) {
                const int k = ka + i;
                if (nloc < 10 && k < 84) Bf[i] = (h16)l2_w[nloc * 84 + k];
            }
            acc = __builtin_amdgcn_mfma_f32_16x16x32_f16(A, Bf, acc, 0, 0, 0);
        }
        if (nloc < 10) {
            #pragma unroll
            for (int r = 0; r < 4; ++r) {
                const int img = q4 * 4 + r;
                if (img < nimg)
                    out[(size_t)(img0 + img) * 10 + nloc] = acc[r] + l2b_s[nloc];
            }
        }
    }
}

extern "C" void kernel_launch(void* const* d_in, const int* in_sizes, int n_in,
                              void* d_out, int out_size, void* d_ws, size_t ws_size,
                              hipStream_t stream) {
    const float* x     = (const float*)d_in[0];
    const float* c1_w  = (const float*)d_in[1];
    const float* c1_b  = (const float*)d_in[2];
    const float* c3_w3 = (const float*)d_in[3];
    const float* c3_b3 = (const float*)d_in[4];
    const float* c3_w4 = (const float*)d_in[5];
    const float* c3_b4 = (const float*)d_in[6];
    const float* c3_w6 = (const float*)d_in[7];
    const float* c3_b6 = (const float*)d_in[8];
    const float* c5_w  = (const float*)d_in[9];
    const float* c5_b  = (const float*)d_in[10];
    const float* l1_w  = (const float*)d_in[11];
    const float* l1_b  = (const float*)d_in[12];
    const float* l2_w  = (const float*)d_in[13];
    const float* l2_b  = (const float*)d_in[14];
    float* out = (float*)d_out;

    const int B = in_sizes[0] / 1024;   // [B,1,32,32]

    // ws: s2 f16 interleaved [B][1576] | s4 f16 [B][400]
    h16* s2g = (h16*)d_ws;
    h16* s4g = (h16*)((char*)d_ws + (size_t)B * S2IMGH * 2);

    k_c1<<<(B + C1_IMG - 1) / C1_IMG, 256, 0, stream>>>(x, c1_w, c1_b, s2g, B);
    k_c3<<<(B + 15) / 16, 256, 0, stream>>>(s2g, c3_w3, c3_b3, c3_w4, c3_b4,
                                            c3_w6, c3_b6, s4g, B);
    k_tail<<<(B + KT_IMG - 1) / KT_IMG, 256, 0, stream>>>(s4g, c5_w, c5_b,
                                                          l1_w, l1_b, l2_w, l2_b, out, B);
}